// Round 5
// baseline (653.447 us; speedup 1.0000x reference)
//
#include <hip/hip_runtime.h>

#define N_NODES 100000
#define N_EDGES 1600000
#define F 128

// bucketed CSR build
#define BSHIFT 11
#define BNODES 2048                      // nodes per bucket
#define NBUCK 49                         // ceil(100000/2048)
#define P1_BLOCKS 128
#define P1_TPB 256
#define EPB1 (N_EDGES / P1_BLOCKS)       // 12500 edges per pass-1 block
#define CAPB 384                         // staging capacity per (bucket, block), pairs
#define P2_TPB 1024
#define SRC_SHIFT 13                     // src-block = src>>13 (8192 nodes = 2 MB window)
#define NSPASS 13                        // ceil(100000/8192)

typedef _Float16 f16x8 __attribute__((ext_vector_type(8)));
typedef _Float16 f16x4 __attribute__((ext_vector_type(4)));
typedef float f32x4 __attribute__((ext_vector_type(4)));

// ---------------- pass 1: partition edges into block-private bucket segments ----------------
__global__ __launch_bounds__(P1_TPB) void k_part(const int* __restrict__ src,
                                                 const int* __restrict__ dst,
                                                 int2* __restrict__ stage,
                                                 int* __restrict__ pcnt) {
    __shared__ int cnt[NBUCK];
    int t = threadIdx.x, blk = blockIdx.x;
    if (t < NBUCK) cnt[t] = 0;
    __syncthreads();
    int base = blk * EPB1;
    for (int i = t; i < EPB1; i += P1_TPB) {
        int e = base + i;
        int s = src[e], d = dst[e];
        int b = d >> BSHIFT;
        int pos = atomicAdd(&cnt[b], 1);
        if (pos < CAPB) stage[((long)b * P1_BLOCKS + blk) * CAPB + pos] = make_int2(s, d);
    }
    __syncthreads();
    if (t < NBUCK) pcnt[t * P1_BLOCKS + blk] = min(cnt[t], CAPB);
}

// ---------------- bucket totals -> exclusive bases ----------------
__global__ void k_bucketsum(const int* __restrict__ pcnt, int* __restrict__ bbase,
                            int* __restrict__ row_start) {
    __shared__ int tot[64];
    int b = threadIdx.x;
    int s = 0;
    if (b < NBUCK)
        for (int i = 0; i < P1_BLOCKS; i++) s += pcnt[b * P1_BLOCKS + i];
    tot[b] = s;
    __syncthreads();
    if (b == 0) {
        int acc = 0;
        for (int i = 0; i < NBUCK; i++) {
            bbase[i] = acc;
            acc += tot[i];
        }
        bbase[NBUCK] = acc;
        row_start[N_NODES] = acc;  // == N_EDGES (all edges staged)
    }
}

// ---------------- pass 2: per-bucket CSR; phase C scatters in src-block order ----------------
__global__ __launch_bounds__(P2_TPB) void k_build(const int2* __restrict__ stage,
                                                  const int* __restrict__ pcnt,
                                                  const int* __restrict__ bbase,
                                                  int* __restrict__ row_start,
                                                  int* __restrict__ esrc) {
    __shared__ int cnt[BNODES];
    __shared__ int scanw[P2_TPB / 64];
    int b = blockIdx.x, t = threadIdx.x;
    int nodeBase = b << BSHIFT;
    for (int i = t; i < BNODES; i += P2_TPB) cnt[i] = 0;
    __syncthreads();
    int grp = t >> 8, gt = t & 255;  // 4 groups x 256 threads
    // phase A: count per local node
    for (int s = grp; s < P1_BLOCKS; s += 4) {
        int n = pcnt[b * P1_BLOCKS + s];
        const int2* seg = &stage[((long)b * P1_BLOCKS + s) * CAPB];
        for (int i = gt; i < n; i += 256) atomicAdd(&cnt[seg[i].y & (BNODES - 1)], 1);
    }
    __syncthreads();
    // phase B: exclusive scan
    int c0 = cnt[2 * t], c1 = cnt[2 * t + 1];
    int v = c0 + c1;
    int lane = t & 63, wv = t >> 6;
    int x = v;
#pragma unroll
    for (int off = 1; off < 64; off <<= 1) {
        int y = __shfl_up(x, off, 64);
        if (lane >= off) x += y;
    }
    if (lane == 63) scanw[wv] = x;
    __syncthreads();
    if (t == 0) {
        int acc = 0;
        for (int i = 0; i < P2_TPB / 64; i++) {
            int y = scanw[i];
            scanw[i] = acc;
            acc += y;
        }
    }
    __syncthreads();
    int excl = x - v + scanw[wv];
    int base0 = bbase[b];
    int n0 = nodeBase + 2 * t;
    if (n0 < N_NODES) row_start[n0] = base0 + excl;
    if (n0 + 1 < N_NODES) row_start[n0 + 1] = base0 + excl + c0;
    cnt[2 * t] = excl;
    cnt[2 * t + 1] = excl + c0;
    __syncthreads();
    // phase C: scatter src into bucket region, in src-block order (13 sub-passes)
    for (int p = 0; p < NSPASS; p++) {
        for (int s = grp; s < P1_BLOCKS; s += 4) {
            int n = pcnt[b * P1_BLOCKS + s];
            const int2* seg = &stage[((long)b * P1_BLOCKS + s) * CAPB];
            for (int i = gt; i < n; i += 256) {
                int2 pr = seg[i];
                if ((pr.x >> SRC_SHIFT) == p) {
                    int pos = atomicAdd(&cnt[pr.y & (BNODES - 1)], 1);
                    esrc[base0 + pos] = pr.x;
                }
            }
        }
        __syncthreads();
    }
}

// ---------------- dtype prep (node-major fp16) ----------------
__global__ void k_cast(const float* __restrict__ x, _Float16* __restrict__ xh, int n4) {
    int i = blockIdx.x * blockDim.x + threadIdx.x;
    if (i < n4) {
        float4 v = ((const float4*)x)[i];
        f16x4 h;
        h.x = (_Float16)v.x; h.y = (_Float16)v.y;
        h.z = (_Float16)v.z; h.w = (_Float16)v.w;
        ((f16x4*)xh)[i] = h;
    }
}

// Wt[n][k] fp16 for both layers in one launch
__global__ void k_prepw(const float* __restrict__ Ws1, const float* __restrict__ Wn1,
                        const float* __restrict__ Ws2, const float* __restrict__ Wn2,
                        _Float16* __restrict__ Wt1, _Float16* __restrict__ Wt2) {
    int i = blockIdx.x * blockDim.x + threadIdx.x;  // 0..65535
    int which = i >> 15;
    int j = i & 32767;
    int n = j >> 8;
    int k = j & 255;
    const float* Ws = which ? Ws2 : Ws1;
    const float* Wn = which ? Wn2 : Wn1;
    _Float16* Wt = which ? Wt2 : Wt1;
    float v = (k < 128) ? Ws[k * F + n] : Wn[(k - 128) * F + n];
    Wt[n * 256 + k] = (_Float16)v;
}

// ---------------- aggregation: wave per node, 256 B coalesced rows, src-sorted edges ----------------
// lane: sub = lane>>5 (edge parity), col = lane&31 (f16x4 = 8 B); 8 edges per iteration.
__global__ __launch_bounds__(256) void k_agg(const f16x4* __restrict__ xf,
                                             const int* __restrict__ row_start,
                                             const int* __restrict__ esrc,
                                             f16x4* __restrict__ out) {
    int wave = (int)((blockIdx.x * blockDim.x + threadIdx.x) >> 6);
    int lane = threadIdx.x & 63;
    if (wave >= N_NODES) return;
    int sub = lane >> 5, col = lane & 31;
    int beg = row_start[wave], end = row_start[wave + 1];
    float ax = 0.f, ay = 0.f, az = 0.f, aw = 0.f;
    int j = beg;
    for (; j + 8 <= end; j += 8) {
        int e0 = esrc[j + sub], e1 = esrc[j + 2 + sub];
        int e2 = esrc[j + 4 + sub], e3 = esrc[j + 6 + sub];
        f16x4 v0 = xf[(long)e0 * 32 + col];
        f16x4 v1 = xf[(long)e1 * 32 + col];
        f16x4 v2 = xf[(long)e2 * 32 + col];
        f16x4 v3 = xf[(long)e3 * 32 + col];
        ax += (float)v0.x + (float)v1.x + (float)v2.x + (float)v3.x;
        ay += (float)v0.y + (float)v1.y + (float)v2.y + (float)v3.y;
        az += (float)v0.z + (float)v1.z + (float)v2.z + (float)v3.z;
        aw += (float)v0.w + (float)v1.w + (float)v2.w + (float)v3.w;
    }
    for (; j + 4 <= end; j += 4) {
        int e0 = esrc[j + sub], e1 = esrc[j + 2 + sub];
        f16x4 v0 = xf[(long)e0 * 32 + col];
        f16x4 v1 = xf[(long)e1 * 32 + col];
        ax += (float)v0.x + (float)v1.x;
        ay += (float)v0.y + (float)v1.y;
        az += (float)v0.z + (float)v1.z;
        aw += (float)v0.w + (float)v1.w;
    }
    for (; j < end; j += 2) {
        if (j + sub < end) {
            f16x4 v = xf[(long)esrc[j + sub] * 32 + col];
            ax += (float)v.x; ay += (float)v.y; az += (float)v.z; aw += (float)v.w;
        }
    }
    ax += __shfl_xor(ax, 32, 64);
    ay += __shfl_xor(ay, 32, 64);
    az += __shfl_xor(az, 32, 64);
    aw += __shfl_xor(aw, 32, 64);
    if (sub == 0) {
        float inv = (end > beg) ? 1.0f / (float)(end - beg) : 0.0f;
        f16x4 r;
        r.x = (_Float16)(ax * inv);
        r.y = (_Float16)(ay * inv);
        r.z = (_Float16)(az * inv);
        r.w = (_Float16)(aw * inv);
        out[(long)wave * 32 + col] = r;
    }
}

// ---------------- MFMA GEMM (node-major A, B staged in LDS fragment-order) ----------------
template <bool FINAL>
__global__ __launch_bounds__(256, 2) void k_gemm_mfma(
    const _Float16* __restrict__ Aself, const _Float16* __restrict__ Aneigh,
    const _Float16* __restrict__ Wt, const float* __restrict__ bias,
    _Float16* __restrict__ Hout, const float* __restrict__ Wf,
    const float* __restrict__ bf, float* __restrict__ Out) {
    const int M = N_NODES;
    __shared__ _Float16 Wl[4096 * 8];  // 64 KB
    int w = threadIdx.x >> 6;
    int lane = threadIdx.x & 63;
    int q = lane >> 4;
    int ln = lane & 15;
    int rBase = blockIdx.x * 128 + w * 32;

#pragma unroll
    for (int i = 0; i < 16; i++) {
        int s = threadIdx.x + i * 256;
        int L = s & 63, ct = (s >> 6) & 7, ks = s >> 9;
        int g = (ct * 16 + (L & 15)) * 256 + ks * 32 + (L >> 4) * 8;
        *(f16x8*)&Wl[s * 8] = *(const f16x8*)&Wt[g];
    }

    f32x4 acc[2][8];
#pragma unroll
    for (int rt = 0; rt < 2; rt++)
#pragma unroll
        for (int ct = 0; ct < 8; ct++) acc[rt][ct] = (f32x4){0.f, 0.f, 0.f, 0.f};

    __syncthreads();

    for (int ks = 0; ks < 8; ks++) {
        const _Float16* Abase = (ks < 4) ? Aself : Aneigh;
        int k0 = (ks & 3) * 32;
        f16x8 b[8];
#pragma unroll
        for (int ct = 0; ct < 8; ct++)
            b[ct] = *(const f16x8*)&Wl[((ks * 8 + ct) * 64 + lane) * 8];
#pragma unroll
        for (int rt = 0; rt < 2; rt++) {
            int row = rBase + rt * 16 + ln;
            f16x8 a = {};
            if (row < M) a = *(const f16x8*)&Abase[(long)row * F + k0 + q * 8];
#pragma unroll
            for (int ct = 0; ct < 8; ct++)
                acc[rt][ct] = __builtin_amdgcn_mfma_f32_16x16x32_f16(a, b[ct], acc[rt][ct], 0, 0, 0);
        }
    }

    float bv[8];
#pragma unroll
    for (int ct = 0; ct < 8; ct++) bv[ct] = bias[ct * 16 + ln];

    if (!FINAL) {
#pragma unroll
        for (int rt = 0; rt < 2; rt++) {
#pragma unroll
            for (int r = 0; r < 4; r++) {
                int row = rBase + rt * 16 + q * 4 + r;
                if (row < M) {
#pragma unroll
                    for (int ct = 0; ct < 8; ct++) {
                        float h = acc[rt][ct][r] + bv[ct];
                        h = h > 0.f ? h : 0.f;
                        Hout[(long)row * F + ct * 16 + ln] = (_Float16)h;
                    }
                }
            }
        }
    } else {
        float wf0[8], wf1[8];
#pragma unroll
        for (int ct = 0; ct < 8; ct++) {
            int c = ct * 16 + ln;
            wf0[ct] = Wf[c * 2 + 0];
            wf1[ct] = Wf[c * 2 + 1];
        }
        float bf0 = bf[0], bf1 = bf[1];
#pragma unroll
        for (int rt = 0; rt < 2; rt++) {
#pragma unroll
            for (int r = 0; r < 4; r++) {
                int row = rBase + rt * 16 + q * 4 + r;
                float p0 = 0.f, p1 = 0.f;
#pragma unroll
                for (int ct = 0; ct < 8; ct++) {
                    float h = acc[rt][ct][r] + bv[ct];
                    h = h > 0.f ? h : 0.f;
                    p0 += h * wf0[ct];
                    p1 += h * wf1[ct];
                }
#pragma unroll
                for (int off = 1; off < 16; off <<= 1) {
                    p0 += __shfl_xor(p0, off, 64);
                    p1 += __shfl_xor(p1, off, 64);
                }
                if (ln == 0 && row < M) {
                    Out[(long)row * 2 + 0] = p0 + bf0;
                    Out[(long)row * 2 + 1] = p1 + bf1;
                }
            }
        }
    }
}

// ---------------- launch ----------------
extern "C" void kernel_launch(void* const* d_in, const int* in_sizes, int n_in,
                              void* d_out, int out_size, void* d_ws, size_t ws_size,
                              hipStream_t stream) {
    const float* x   = (const float*)d_in[0];
    const float* Ws1 = (const float*)d_in[1];
    const float* Wn1 = (const float*)d_in[2];
    const float* b1  = (const float*)d_in[3];
    const float* Ws2 = (const float*)d_in[4];
    const float* Wn2 = (const float*)d_in[5];
    const float* b2  = (const float*)d_in[6];
    const float* Wf  = (const float*)d_in[7];
    const float* bf  = (const float*)d_in[8];
    const int* src   = (const int*)d_in[9];
    const int* dst   = (const int*)d_in[10];
    float* out = (float*)d_out;

    char* ws = (char*)d_ws;
    int*      row_start = (int*)(ws + 0);          // 400,016
    int*      bbase     = (int*)(ws + 400016);     // 256
    int*      pcnt      = (int*)(ws + 400272);     // 25,088
    int2*     stage     = (int2*)(ws + 425360);    // 19,267,584
    int*      esrc      = (int*)(ws + 19692944);   // 6,400,000
    _Float16* xh        = (_Float16*)(ws + 26092944);   // 25,600,000 (node-major)
    _Float16* hneigh    = (_Float16*)(ws + 51692944);   // 25,600,000
    _Float16* h1        = (_Float16*)(ws + 77292944);   // 25,600,000
    _Float16* Wt1       = (_Float16*)(ws + 102892944);  // 65,536
    _Float16* Wt2       = (_Float16*)(ws + 102958480);  // 65,536

    const int TPB = 256;
    // CSR build (src-block-sorted rows)
    k_part<<<P1_BLOCKS, P1_TPB, 0, stream>>>(src, dst, stage, pcnt);
    k_bucketsum<<<1, 64, 0, stream>>>(pcnt, bbase, row_start);
    k_build<<<NBUCK, P2_TPB, 0, stream>>>(stage, pcnt, bbase, row_start, esrc);

    // dtype prep
    k_cast<<<(N_NODES * F / 4 + TPB - 1) / TPB, TPB, 0, stream>>>(x, xh, N_NODES * F / 4);
    k_prepw<<<256, 256, 0, stream>>>(Ws1, Wn1, Ws2, Wn2, Wt1, Wt2);

    // layer 1
    k_agg<<<(N_NODES + 3) / 4, 256, 0, stream>>>((const f16x4*)xh, row_start, esrc,
                                                 (f16x4*)hneigh);
    k_gemm_mfma<false><<<(N_NODES + 127) / 128, 256, 0, stream>>>(
        xh, hneigh, Wt1, b1, h1, nullptr, nullptr, nullptr);
    // layer 2 + fused final projection
    k_agg<<<(N_NODES + 3) / 4, 256, 0, stream>>>((const f16x4*)h1, row_start, esrc,
                                                 (f16x4*)hneigh);
    k_gemm_mfma<true><<<(N_NODES + 127) / 128, 256, 0, stream>>>(
        h1, hneigh, Wt2, b2, nullptr, Wf, bf, out);
}

// Round 6
// 389.922 us; speedup vs baseline: 1.6758x; 1.6758x over previous
//
#include <hip/hip_runtime.h>

#define N_NODES 100000
#define N_EDGES 1600000
#define F 128

// bucketed CSR build with in-bucket counting sort by src-block
#define BSHIFT 9
#define BNODES 512                       // nodes per bucket
#define NBUCK 196                        // ceil(100000/512)
#define P1_BLOCKS 128
#define P1_TPB 256
#define EPB1 (N_EDGES / P1_BLOCKS)       // 12500 edges per pass-1 block
#define CAPB 160                         // staging capacity per (bucket, block); mean 64, +12 sigma
#define SRC_SHIFT 12                     // src-block granularity: 4096 nodes = 1 MB fp16 window
#define NSPLIT 25                        // ceil(100000/4096)
#define KEYS (BNODES * NSPLIT)           // 12800 counters = 50 KB LDS
#define P2_TPB 512

typedef _Float16 f16x8 __attribute__((ext_vector_type(8)));
typedef _Float16 f16x4 __attribute__((ext_vector_type(4)));
typedef float f32x4 __attribute__((ext_vector_type(4)));

// ---------------- pass 1: partition packed edges into block-private bucket segments ----------------
__global__ __launch_bounds__(P1_TPB) void k_part(const int* __restrict__ src,
                                                 const int* __restrict__ dst,
                                                 int* __restrict__ stage,
                                                 int* __restrict__ pcnt) {
    __shared__ int cnt[NBUCK];
    int t = threadIdx.x, blk = blockIdx.x;
    if (t < NBUCK) cnt[t] = 0;
    __syncthreads();
    int base = blk * EPB1;
    for (int i = t; i < EPB1; i += P1_TPB) {
        int e = base + i;
        int s = src[e], d = dst[e];
        int b = d >> BSHIFT;
        int pos = atomicAdd(&cnt[b], 1);
        if (pos < CAPB)
            stage[((long)b * P1_BLOCKS + blk) * CAPB + pos] = (s << BSHIFT) | (d & (BNODES - 1));
    }
    __syncthreads();
    if (t < NBUCK) pcnt[t * P1_BLOCKS + blk] = min(cnt[t], CAPB);
}

// ---------------- bucket totals -> exclusive bases ----------------
__global__ void k_bucketsum(const int* __restrict__ pcnt, int* __restrict__ bbase,
                            int* __restrict__ row_start) {
    __shared__ int tot[NBUCK];
    int t = threadIdx.x;  // 256 threads
    for (int b = t; b < NBUCK; b += 256) {
        int s = 0;
        for (int i = 0; i < P1_BLOCKS; i++) s += pcnt[b * P1_BLOCKS + i];
        tot[b] = s;
    }
    __syncthreads();
    if (t == 0) {
        int acc = 0;
        for (int i = 0; i < NBUCK; i++) {
            bbase[i] = acc;
            acc += tot[i];
        }
        bbase[NBUCK] = acc;
        row_start[N_NODES] = acc;  // == N_EDGES
    }
}

// ---------------- pass 2: per-bucket counting sort on (local_dst, src_block) ----------------
__global__ __launch_bounds__(P2_TPB) void k_build(const int* __restrict__ stage,
                                                  const int* __restrict__ pcnt,
                                                  const int* __restrict__ bbase,
                                                  int* __restrict__ row_start,
                                                  int* __restrict__ esrc) {
    __shared__ int cnt[KEYS];
    __shared__ int scanw[P2_TPB / 64];
    int b = blockIdx.x, t = threadIdx.x;
    int nodeBase = b * BNODES;
    for (int i = t; i < KEYS; i += P2_TPB) cnt[i] = 0;
    __syncthreads();
    int grp = t >> 7, gt = t & 127;  // 4 groups x 128 threads
    // phase A: count per (node, src_block) key
    for (int s = grp; s < P1_BLOCKS; s += 4) {
        int n = pcnt[b * P1_BLOCKS + s];
        const int* seg = &stage[((long)b * P1_BLOCKS + s) * CAPB];
        for (int i = gt; i < n; i += 128) {
            int pk = seg[i];
            atomicAdd(&cnt[(pk & (BNODES - 1)) * NSPLIT + (pk >> (BSHIFT + SRC_SHIFT))], 1);
        }
    }
    __syncthreads();
    // phase B: exclusive scan over KEYS counters, 25/thread
    int kbase = t * 25;
    int sum = 0;
#pragma unroll
    for (int i = 0; i < 25; i++) sum += cnt[kbase + i];
    int lane = t & 63, wv = t >> 6;
    int x = sum;
#pragma unroll
    for (int off = 1; off < 64; off <<= 1) {
        int y = __shfl_up(x, off, 64);
        if (lane >= off) x += y;
    }
    if (lane == 63) scanw[wv] = x;
    __syncthreads();
    if (t == 0) {
        int acc = 0;
        for (int i = 0; i < P2_TPB / 64; i++) {
            int y = scanw[i];
            scanw[i] = acc;
            acc += y;
        }
    }
    __syncthreads();
    int run = x - sum + scanw[wv];  // exclusive prefix for this thread's key range
#pragma unroll
    for (int i = 0; i < 25; i++) {
        int c = cnt[kbase + i];
        cnt[kbase + i] = run;  // becomes cursor
        run += c;
    }
    __syncthreads();
    int base0 = bbase[b];
    // row_start: cursor at each node's first key
    {
        int node = nodeBase + t;  // P2_TPB == BNODES
        if (t < BNODES && node < N_NODES) row_start[node] = base0 + cnt[t * NSPLIT];
    }
    __syncthreads();
    // phase C: single scatter pass -> rows sorted by src_block
    for (int s = grp; s < P1_BLOCKS; s += 4) {
        int n = pcnt[b * P1_BLOCKS + s];
        const int* seg = &stage[((long)b * P1_BLOCKS + s) * CAPB];
        for (int i = gt; i < n; i += 128) {
            int pk = seg[i];
            int pos = atomicAdd(&cnt[(pk & (BNODES - 1)) * NSPLIT + (pk >> (BSHIFT + SRC_SHIFT))], 1);
            esrc[base0 + pos] = pk >> BSHIFT;
        }
    }
}

// ---------------- dtype prep (node-major fp16) ----------------
__global__ void k_cast(const float* __restrict__ x, _Float16* __restrict__ xh, int n4) {
    int i = blockIdx.x * blockDim.x + threadIdx.x;
    if (i < n4) {
        float4 v = ((const float4*)x)[i];
        f16x4 h;
        h.x = (_Float16)v.x; h.y = (_Float16)v.y;
        h.z = (_Float16)v.z; h.w = (_Float16)v.w;
        ((f16x4*)xh)[i] = h;
    }
}

// Wt[n][k] fp16 for both layers in one launch
__global__ void k_prepw(const float* __restrict__ Ws1, const float* __restrict__ Wn1,
                        const float* __restrict__ Ws2, const float* __restrict__ Wn2,
                        _Float16* __restrict__ Wt1, _Float16* __restrict__ Wt2) {
    int i = blockIdx.x * blockDim.x + threadIdx.x;  // 0..65535
    int which = i >> 15;
    int j = i & 32767;
    int n = j >> 8;
    int k = j & 255;
    const float* Ws = which ? Ws2 : Ws1;
    const float* Wn = which ? Wn2 : Wn1;
    _Float16* Wt = which ? Wt2 : Wt1;
    float v = (k < 128) ? Ws[k * F + n] : Wn[(k - 128) * F + n];
    Wt[n * 256 + k] = (_Float16)v;
}

// ---------------- aggregation: wave per node, 256 B coalesced rows, src-sorted edges ----------------
__global__ __launch_bounds__(256) void k_agg(const f16x4* __restrict__ xf,
                                             const int* __restrict__ row_start,
                                             const int* __restrict__ esrc,
                                             f16x4* __restrict__ out) {
    int wave = (int)((blockIdx.x * blockDim.x + threadIdx.x) >> 6);
    int lane = threadIdx.x & 63;
    if (wave >= N_NODES) return;
    int sub = lane >> 5, col = lane & 31;
    int beg = row_start[wave], end = row_start[wave + 1];
    float ax = 0.f, ay = 0.f, az = 0.f, aw = 0.f;
    int j = beg;
    for (; j + 8 <= end; j += 8) {
        int e0 = esrc[j + sub], e1 = esrc[j + 2 + sub];
        int e2 = esrc[j + 4 + sub], e3 = esrc[j + 6 + sub];
        f16x4 v0 = xf[(long)e0 * 32 + col];
        f16x4 v1 = xf[(long)e1 * 32 + col];
        f16x4 v2 = xf[(long)e2 * 32 + col];
        f16x4 v3 = xf[(long)e3 * 32 + col];
        ax += (float)v0.x + (float)v1.x + (float)v2.x + (float)v3.x;
        ay += (float)v0.y + (float)v1.y + (float)v2.y + (float)v3.y;
        az += (float)v0.z + (float)v1.z + (float)v2.z + (float)v3.z;
        aw += (float)v0.w + (float)v1.w + (float)v2.w + (float)v3.w;
    }
    for (; j + 4 <= end; j += 4) {
        int e0 = esrc[j + sub], e1 = esrc[j + 2 + sub];
        f16x4 v0 = xf[(long)e0 * 32 + col];
        f16x4 v1 = xf[(long)e1 * 32 + col];
        ax += (float)v0.x + (float)v1.x;
        ay += (float)v0.y + (float)v1.y;
        az += (float)v0.z + (float)v1.z;
        aw += (float)v0.w + (float)v1.w;
    }
    for (; j < end; j += 2) {
        if (j + sub < end) {
            f16x4 v = xf[(long)esrc[j + sub] * 32 + col];
            ax += (float)v.x; ay += (float)v.y; az += (float)v.z; aw += (float)v.w;
        }
    }
    ax += __shfl_xor(ax, 32, 64);
    ay += __shfl_xor(ay, 32, 64);
    az += __shfl_xor(az, 32, 64);
    aw += __shfl_xor(aw, 32, 64);
    if (sub == 0) {
        float inv = (end > beg) ? 1.0f / (float)(end - beg) : 0.0f;
        f16x4 r;
        r.x = (_Float16)(ax * inv);
        r.y = (_Float16)(ay * inv);
        r.z = (_Float16)(az * inv);
        r.w = (_Float16)(aw * inv);
        out[(long)wave * 32 + col] = r;
    }
}

// ---------------- MFMA GEMM (node-major A, B staged in LDS fragment-order) ----------------
template <bool FINAL>
__global__ __launch_bounds__(256, 2) void k_gemm_mfma(
    const _Float16* __restrict__ Aself, const _Float16* __restrict__ Aneigh,
    const _Float16* __restrict__ Wt, const float* __restrict__ bias,
    _Float16* __restrict__ Hout, const float* __restrict__ Wf,
    const float* __restrict__ bf, float* __restrict__ Out) {
    const int M = N_NODES;
    __shared__ _Float16 Wl[4096 * 8];  // 64 KB
    int w = threadIdx.x >> 6;
    int lane = threadIdx.x & 63;
    int q = lane >> 4;
    int ln = lane & 15;
    int rBase = blockIdx.x * 128 + w * 32;

#pragma unroll
    for (int i = 0; i < 16; i++) {
        int s = threadIdx.x + i * 256;
        int L = s & 63, ct = (s >> 6) & 7, ks = s >> 9;
        int g = (ct * 16 + (L & 15)) * 256 + ks * 32 + (L >> 4) * 8;
        *(f16x8*)&Wl[s * 8] = *(const f16x8*)&Wt[g];
    }

    f32x4 acc[2][8];
#pragma unroll
    for (int rt = 0; rt < 2; rt++)
#pragma unroll
        for (int ct = 0; ct < 8; ct++) acc[rt][ct] = (f32x4){0.f, 0.f, 0.f, 0.f};

    __syncthreads();

    for (int ks = 0; ks < 8; ks++) {
        const _Float16* Abase = (ks < 4) ? Aself : Aneigh;
        int k0 = (ks & 3) * 32;
        f16x8 b[8];
#pragma unroll
        for (int ct = 0; ct < 8; ct++)
            b[ct] = *(const f16x8*)&Wl[((ks * 8 + ct) * 64 + lane) * 8];
#pragma unroll
        for (int rt = 0; rt < 2; rt++) {
            int row = rBase + rt * 16 + ln;
            f16x8 a = {};
            if (row < M) a = *(const f16x8*)&Abase[(long)row * F + k0 + q * 8];
#pragma unroll
            for (int ct = 0; ct < 8; ct++)
                acc[rt][ct] = __builtin_amdgcn_mfma_f32_16x16x32_f16(a, b[ct], acc[rt][ct], 0, 0, 0);
        }
    }

    float bv[8];
#pragma unroll
    for (int ct = 0; ct < 8; ct++) bv[ct] = bias[ct * 16 + ln];

    if (!FINAL) {
#pragma unroll
        for (int rt = 0; rt < 2; rt++) {
#pragma unroll
            for (int r = 0; r < 4; r++) {
                int row = rBase + rt * 16 + q * 4 + r;
                if (row < M) {
#pragma unroll
                    for (int ct = 0; ct < 8; ct++) {
                        float h = acc[rt][ct][r] + bv[ct];
                        h = h > 0.f ? h : 0.f;
                        Hout[(long)row * F + ct * 16 + ln] = (_Float16)h;
                    }
                }
            }
        }
    } else {
        float wf0[8], wf1[8];
#pragma unroll
        for (int ct = 0; ct < 8; ct++) {
            int c = ct * 16 + ln;
            wf0[ct] = Wf[c * 2 + 0];
            wf1[ct] = Wf[c * 2 + 1];
        }
        float bf0 = bf[0], bf1 = bf[1];
#pragma unroll
        for (int rt = 0; rt < 2; rt++) {
#pragma unroll
            for (int r = 0; r < 4; r++) {
                int row = rBase + rt * 16 + q * 4 + r;
                float p0 = 0.f, p1 = 0.f;
#pragma unroll
                for (int ct = 0; ct < 8; ct++) {
                    float h = acc[rt][ct][r] + bv[ct];
                    h = h > 0.f ? h : 0.f;
                    p0 += h * wf0[ct];
                    p1 += h * wf1[ct];
                }
#pragma unroll
                for (int off = 1; off < 16; off <<= 1) {
                    p0 += __shfl_xor(p0, off, 64);
                    p1 += __shfl_xor(p1, off, 64);
                }
                if (ln == 0 && row < M) {
                    Out[(long)row * 2 + 0] = p0 + bf0;
                    Out[(long)row * 2 + 1] = p1 + bf1;
                }
            }
        }
    }
}

// ---------------- launch ----------------
extern "C" void kernel_launch(void* const* d_in, const int* in_sizes, int n_in,
                              void* d_out, int out_size, void* d_ws, size_t ws_size,
                              hipStream_t stream) {
    const float* x   = (const float*)d_in[0];
    const float* Ws1 = (const float*)d_in[1];
    const float* Wn1 = (const float*)d_in[2];
    const float* b1  = (const float*)d_in[3];
    const float* Ws2 = (const float*)d_in[4];
    const float* Wn2 = (const float*)d_in[5];
    const float* b2  = (const float*)d_in[6];
    const float* Wf  = (const float*)d_in[7];
    const float* bf  = (const float*)d_in[8];
    const int* src   = (const int*)d_in[9];
    const int* dst   = (const int*)d_in[10];
    float* out = (float*)d_out;

    char* ws = (char*)d_ws;
    int*      row_start = (int*)(ws + 0);               // 400,016
    int*      bbase     = (int*)(ws + 400016);          // 800 (197 ints)
    int*      pcnt      = (int*)(ws + 400816);          // 100,352 (196*128)
    int*      stage     = (int*)(ws + 501184);          // 16,056,320 (196*128*160*4)
    int*      esrc      = (int*)(ws + 16557504);        // 6,400,000
    _Float16* xh        = (_Float16*)(ws + 22957504);   // 25,600,000
    _Float16* hneigh    = (_Float16*)(ws + 48557504);   // 25,600,000
    _Float16* h1        = (_Float16*)(ws + 74157504);   // 25,600,000
    _Float16* Wt1       = (_Float16*)(ws + 99757504);   // 65,536
    _Float16* Wt2       = (_Float16*)(ws + 99823040);   // 65,536
    // total ~99.9 MB

    const int TPB = 256;
    // CSR build (src-block-sorted rows, single-pass counting sort)
    k_part<<<P1_BLOCKS, P1_TPB, 0, stream>>>(src, dst, stage, pcnt);
    k_bucketsum<<<1, 256, 0, stream>>>(pcnt, bbase, row_start);
    k_build<<<NBUCK, P2_TPB, 0, stream>>>(stage, pcnt, bbase, row_start, esrc);

    // dtype prep
    k_cast<<<(N_NODES * F / 4 + TPB - 1) / TPB, TPB, 0, stream>>>(x, xh, N_NODES * F / 4);
    k_prepw<<<256, 256, 0, stream>>>(Ws1, Wn1, Ws2, Wn2, Wt1, Wt2);

    // layer 1
    k_agg<<<(N_NODES + 3) / 4, 256, 0, stream>>>((const f16x4*)xh, row_start, esrc,
                                                 (f16x4*)hneigh);
    k_gemm_mfma<false><<<(N_NODES + 127) / 128, 256, 0, stream>>>(
        xh, hneigh, Wt1, b1, h1, nullptr, nullptr, nullptr);
    // layer 2 + fused final projection
    k_agg<<<(N_NODES + 3) / 4, 256, 0, stream>>>((const f16x4*)h1, row_start, esrc,
                                                 (f16x4*)hneigh);
    k_gemm_mfma<true><<<(N_NODES + 127) / 128, 256, 0, stream>>>(
        h1, hneigh, Wt2, b2, nullptr, Wf, bf, out);
}

// Round 7
// 385.118 us; speedup vs baseline: 1.6967x; 1.0125x over previous
//
#include <hip/hip_runtime.h>

#define N_NODES 100000
#define N_EDGES 1600000
#define F 128

// bucketed CSR build with in-bucket counting sort by src-block
#define BSHIFT 9
#define BNODES 512                       // nodes per bucket
#define NBUCK 196                        // ceil(100000/512)
#define P1_BLOCKS 128
#define P1_TPB 256
#define EPB1 (N_EDGES / P1_BLOCKS)       // 12500 edges per pass-1 block
#define CAPB 160                         // staging capacity per (bucket, block)
#define SRC_SHIFT 12                     // src-block granularity: 4096 nodes = 1 MB fp16 window
#define NSPLIT 25                        // ceil(100000/4096)
#define KEYS (BNODES * NSPLIT)           // 12800 counters = 50 KB LDS
#define P2_TPB 512

typedef _Float16 f16x8 __attribute__((ext_vector_type(8)));
typedef _Float16 f16x4 __attribute__((ext_vector_type(4)));
typedef _Float16 f16x2 __attribute__((ext_vector_type(2)));
typedef float f32x4 __attribute__((ext_vector_type(4)));

// ---------------- pass 1: partition packed edges into block-private bucket segments ----------------
__global__ __launch_bounds__(P1_TPB) void k_part(const int* __restrict__ src,
                                                 const int* __restrict__ dst,
                                                 int* __restrict__ stage,
                                                 int* __restrict__ pcnt) {
    __shared__ int cnt[NBUCK];
    int t = threadIdx.x, blk = blockIdx.x;
    if (t < NBUCK) cnt[t] = 0;
    __syncthreads();
    int base = blk * EPB1;
    for (int i = t; i < EPB1; i += P1_TPB) {
        int e = base + i;
        int s = src[e], d = dst[e];
        int b = d >> BSHIFT;
        int pos = atomicAdd(&cnt[b], 1);
        if (pos < CAPB)
            stage[((long)b * P1_BLOCKS + blk) * CAPB + pos] = (s << BSHIFT) | (d & (BNODES - 1));
    }
    __syncthreads();
    if (t < NBUCK) pcnt[t * P1_BLOCKS + blk] = min(cnt[t], CAPB);
}

// ---------------- bucket totals -> exclusive bases ----------------
__global__ void k_bucketsum(const int* __restrict__ pcnt, int* __restrict__ bbase,
                            int* __restrict__ row_start) {
    __shared__ int tot[NBUCK];
    int t = threadIdx.x;  // 256 threads
    for (int b = t; b < NBUCK; b += 256) {
        int s = 0;
        for (int i = 0; i < P1_BLOCKS; i++) s += pcnt[b * P1_BLOCKS + i];
        tot[b] = s;
    }
    __syncthreads();
    if (t == 0) {
        int acc = 0;
        for (int i = 0; i < NBUCK; i++) {
            bbase[i] = acc;
            acc += tot[i];
        }
        bbase[NBUCK] = acc;
        row_start[N_NODES] = acc;  // == N_EDGES
    }
}

// ---------------- pass 2: per-bucket counting sort on (local_dst, src_block) ----------------
__global__ __launch_bounds__(P2_TPB) void k_build(const int* __restrict__ stage,
                                                  const int* __restrict__ pcnt,
                                                  const int* __restrict__ bbase,
                                                  int* __restrict__ row_start,
                                                  int* __restrict__ esrc) {
    __shared__ int cnt[KEYS];
    __shared__ int scanw[P2_TPB / 64];
    int b = blockIdx.x, t = threadIdx.x;
    int nodeBase = b * BNODES;
    for (int i = t; i < KEYS; i += P2_TPB) cnt[i] = 0;
    __syncthreads();
    int grp = t >> 7, gt = t & 127;  // 4 groups x 128 threads
    for (int s = grp; s < P1_BLOCKS; s += 4) {
        int n = pcnt[b * P1_BLOCKS + s];
        const int* seg = &stage[((long)b * P1_BLOCKS + s) * CAPB];
        for (int i = gt; i < n; i += 128) {
            int pk = seg[i];
            atomicAdd(&cnt[(pk & (BNODES - 1)) * NSPLIT + (pk >> (BSHIFT + SRC_SHIFT))], 1);
        }
    }
    __syncthreads();
    int kbase = t * 25;
    int sum = 0;
#pragma unroll
    for (int i = 0; i < 25; i++) sum += cnt[kbase + i];
    int lane = t & 63, wv = t >> 6;
    int x = sum;
#pragma unroll
    for (int off = 1; off < 64; off <<= 1) {
        int y = __shfl_up(x, off, 64);
        if (lane >= off) x += y;
    }
    if (lane == 63) scanw[wv] = x;
    __syncthreads();
    if (t == 0) {
        int acc = 0;
        for (int i = 0; i < P2_TPB / 64; i++) {
            int y = scanw[i];
            scanw[i] = acc;
            acc += y;
        }
    }
    __syncthreads();
    int run = x - sum + scanw[wv];
#pragma unroll
    for (int i = 0; i < 25; i++) {
        int c = cnt[kbase + i];
        cnt[kbase + i] = run;
        run += c;
    }
    __syncthreads();
    int base0 = bbase[b];
    {
        int node = nodeBase + t;  // P2_TPB == BNODES
        if (t < BNODES && node < N_NODES) row_start[node] = base0 + cnt[t * NSPLIT];
    }
    __syncthreads();
    for (int s = grp; s < P1_BLOCKS; s += 4) {
        int n = pcnt[b * P1_BLOCKS + s];
        const int* seg = &stage[((long)b * P1_BLOCKS + s) * CAPB];
        for (int i = gt; i < n; i += 128) {
            int pk = seg[i];
            int pos = atomicAdd(&cnt[(pk & (BNODES - 1)) * NSPLIT + (pk >> (BSHIFT + SRC_SHIFT))], 1);
            esrc[base0 + pos] = pk >> BSHIFT;
        }
    }
}

// ---------------- dtype prep (node-major fp16) ----------------
__global__ void k_cast(const float* __restrict__ x, _Float16* __restrict__ xh, int n4) {
    int i = blockIdx.x * blockDim.x + threadIdx.x;
    if (i < n4) {
        float4 v = ((const float4*)x)[i];
        f16x4 h;
        h.x = (_Float16)v.x; h.y = (_Float16)v.y;
        h.z = (_Float16)v.z; h.w = (_Float16)v.w;
        ((f16x4*)xh)[i] = h;
    }
}

// Wt[n][k] fp16 for both layers in one launch
__global__ void k_prepw(const float* __restrict__ Ws1, const float* __restrict__ Wn1,
                        const float* __restrict__ Ws2, const float* __restrict__ Wn2,
                        _Float16* __restrict__ Wt1, _Float16* __restrict__ Wt2) {
    int i = blockIdx.x * blockDim.x + threadIdx.x;  // 0..65535
    int which = i >> 15;
    int j = i & 32767;
    int n = j >> 8;
    int k = j & 255;
    const float* Ws = which ? Ws2 : Ws1;
    const float* Wn = which ? Wn2 : Wn1;
    _Float16* Wt = which ? Wt2 : Wt1;
    float v = (k < 128) ? Ws[k * F + n] : Wn[(k - 128) * F + n];
    Wt[n * 256 + k] = (_Float16)v;
}

// ---------------- aggregation: wave per node, edge list in registers, shfl-broadcast ----------------
// Lane l holds edge l's src id; per edge the whole wave gathers one 256 B row
// (f16x2/lane). No dependent esrc loads in the loop; 8 row-gathers in flight.
__global__ __launch_bounds__(256) void k_agg(const f16x2* __restrict__ xf,
                                             const int* __restrict__ row_start,
                                             const int* __restrict__ esrc,
                                             f16x2* __restrict__ out) {
    int wave = (int)((blockIdx.x * blockDim.x + threadIdx.x) >> 6);
    int lane = threadIdx.x & 63;
    if (wave >= N_NODES) return;
    int beg = row_start[wave], end = row_start[wave + 1];
    int deg = end - beg;
    int e = 0;
    if (lane < deg) e = esrc[beg + lane];  // one coalesced load of the whole edge list
    float ax = 0.f, ay = 0.f;
    int n64 = min(deg, 64);
    int i = 0;
    for (; i + 8 <= n64; i += 8) {
        int s0 = __shfl(e, i + 0, 64);
        int s1 = __shfl(e, i + 1, 64);
        int s2 = __shfl(e, i + 2, 64);
        int s3 = __shfl(e, i + 3, 64);
        int s4 = __shfl(e, i + 4, 64);
        int s5 = __shfl(e, i + 5, 64);
        int s6 = __shfl(e, i + 6, 64);
        int s7 = __shfl(e, i + 7, 64);
        f16x2 v0 = xf[(long)s0 * 64 + lane];
        f16x2 v1 = xf[(long)s1 * 64 + lane];
        f16x2 v2 = xf[(long)s2 * 64 + lane];
        f16x2 v3 = xf[(long)s3 * 64 + lane];
        f16x2 v4 = xf[(long)s4 * 64 + lane];
        f16x2 v5 = xf[(long)s5 * 64 + lane];
        f16x2 v6 = xf[(long)s6 * 64 + lane];
        f16x2 v7 = xf[(long)s7 * 64 + lane];
        ax += ((float)v0.x + (float)v1.x) + ((float)v2.x + (float)v3.x) +
              ((float)v4.x + (float)v5.x) + ((float)v6.x + (float)v7.x);
        ay += ((float)v0.y + (float)v1.y) + ((float)v2.y + (float)v3.y) +
              ((float)v4.y + (float)v5.y) + ((float)v6.y + (float)v7.y);
    }
    for (; i + 2 <= n64; i += 2) {
        int s0 = __shfl(e, i + 0, 64);
        int s1 = __shfl(e, i + 1, 64);
        f16x2 v0 = xf[(long)s0 * 64 + lane];
        f16x2 v1 = xf[(long)s1 * 64 + lane];
        ax += (float)v0.x + (float)v1.x;
        ay += (float)v0.y + (float)v1.y;
    }
    for (; i < n64; i++) {
        int s = __shfl(e, i, 64);
        f16x2 v = xf[(long)s * 64 + lane];
        ax += (float)v.x;
        ay += (float)v.y;
    }
    // rare tail: deg > 64
    for (int j = beg + 64; j < end; j++) {
        int s = esrc[j];
        f16x2 v = xf[(long)s * 64 + lane];
        ax += (float)v.x;
        ay += (float)v.y;
    }
    float inv = (deg > 0) ? 1.0f / (float)deg : 0.0f;
    f16x2 r;
    r.x = (_Float16)(ax * inv);
    r.y = (_Float16)(ay * inv);
    out[(long)wave * 64 + lane] = r;
}

// ---------------- MFMA GEMM (node-major A, B staged in LDS fragment-order) ----------------
template <bool FINAL>
__global__ __launch_bounds__(256, 2) void k_gemm_mfma(
    const _Float16* __restrict__ Aself, const _Float16* __restrict__ Aneigh,
    const _Float16* __restrict__ Wt, const float* __restrict__ bias,
    _Float16* __restrict__ Hout, const float* __restrict__ Wf,
    const float* __restrict__ bf, float* __restrict__ Out) {
    const int M = N_NODES;
    __shared__ _Float16 Wl[4096 * 8];  // 64 KB
    int w = threadIdx.x >> 6;
    int lane = threadIdx.x & 63;
    int q = lane >> 4;
    int ln = lane & 15;
    int rBase = blockIdx.x * 128 + w * 32;

#pragma unroll
    for (int i = 0; i < 16; i++) {
        int s = threadIdx.x + i * 256;
        int L = s & 63, ct = (s >> 6) & 7, ks = s >> 9;
        int g = (ct * 16 + (L & 15)) * 256 + ks * 32 + (L >> 4) * 8;
        *(f16x8*)&Wl[s * 8] = *(const f16x8*)&Wt[g];
    }

    f32x4 acc[2][8];
#pragma unroll
    for (int rt = 0; rt < 2; rt++)
#pragma unroll
        for (int ct = 0; ct < 8; ct++) acc[rt][ct] = (f32x4){0.f, 0.f, 0.f, 0.f};

    __syncthreads();

    for (int ks = 0; ks < 8; ks++) {
        const _Float16* Abase = (ks < 4) ? Aself : Aneigh;
        int k0 = (ks & 3) * 32;
        f16x8 b[8];
#pragma unroll
        for (int ct = 0; ct < 8; ct++)
            b[ct] = *(const f16x8*)&Wl[((ks * 8 + ct) * 64 + lane) * 8];
#pragma unroll
        for (int rt = 0; rt < 2; rt++) {
            int row = rBase + rt * 16 + ln;
            f16x8 a = {};
            if (row < M) a = *(const f16x8*)&Abase[(long)row * F + k0 + q * 8];
#pragma unroll
            for (int ct = 0; ct < 8; ct++)
                acc[rt][ct] = __builtin_amdgcn_mfma_f32_16x16x32_f16(a, b[ct], acc[rt][ct], 0, 0, 0);
        }
    }

    float bv[8];
#pragma unroll
    for (int ct = 0; ct < 8; ct++) bv[ct] = bias[ct * 16 + ln];

    if (!FINAL) {
#pragma unroll
        for (int rt = 0; rt < 2; rt++) {
#pragma unroll
            for (int r = 0; r < 4; r++) {
                int row = rBase + rt * 16 + q * 4 + r;
                if (row < M) {
#pragma unroll
                    for (int ct = 0; ct < 8; ct++) {
                        float h = acc[rt][ct][r] + bv[ct];
                        h = h > 0.f ? h : 0.f;
                        Hout[(long)row * F + ct * 16 + ln] = (_Float16)h;
                    }
                }
            }
        }
    } else {
        float wf0[8], wf1[8];
#pragma unroll
        for (int ct = 0; ct < 8; ct++) {
            int c = ct * 16 + ln;
            wf0[ct] = Wf[c * 2 + 0];
            wf1[ct] = Wf[c * 2 + 1];
        }
        float bf0 = bf[0], bf1 = bf[1];
#pragma unroll
        for (int rt = 0; rt < 2; rt++) {
#pragma unroll
            for (int r = 0; r < 4; r++) {
                int row = rBase + rt * 16 + q * 4 + r;
                float p0 = 0.f, p1 = 0.f;
#pragma unroll
                for (int ct = 0; ct < 8; ct++) {
                    float h = acc[rt][ct][r] + bv[ct];
                    h = h > 0.f ? h : 0.f;
                    p0 += h * wf0[ct];
                    p1 += h * wf1[ct];
                }
#pragma unroll
                for (int off = 1; off < 16; off <<= 1) {
                    p0 += __shfl_xor(p0, off, 64);
                    p1 += __shfl_xor(p1, off, 64);
                }
                if (ln == 0 && row < M) {
                    Out[(long)row * 2 + 0] = p0 + bf0;
                    Out[(long)row * 2 + 1] = p1 + bf1;
                }
            }
        }
    }
}

// ---------------- launch ----------------
extern "C" void kernel_launch(void* const* d_in, const int* in_sizes, int n_in,
                              void* d_out, int out_size, void* d_ws, size_t ws_size,
                              hipStream_t stream) {
    const float* x   = (const float*)d_in[0];
    const float* Ws1 = (const float*)d_in[1];
    const float* Wn1 = (const float*)d_in[2];
    const float* b1  = (const float*)d_in[3];
    const float* Ws2 = (const float*)d_in[4];
    const float* Wn2 = (const float*)d_in[5];
    const float* b2  = (const float*)d_in[6];
    const float* Wf  = (const float*)d_in[7];
    const float* bf  = (const float*)d_in[8];
    const int* src   = (const int*)d_in[9];
    const int* dst   = (const int*)d_in[10];
    float* out = (float*)d_out;

    char* ws = (char*)d_ws;
    int*      row_start = (int*)(ws + 0);               // 400,016
    int*      bbase     = (int*)(ws + 400016);          // 800
    int*      pcnt      = (int*)(ws + 400816);          // 100,352
    int*      stage     = (int*)(ws + 501184);          // 16,056,320
    int*      esrc      = (int*)(ws + 16557504);        // 6,400,000
    _Float16* xh        = (_Float16*)(ws + 22957504);   // 25,600,000
    _Float16* hneigh    = (_Float16*)(ws + 48557504);   // 25,600,000
    _Float16* h1        = (_Float16*)(ws + 74157504);   // 25,600,000
    _Float16* Wt1       = (_Float16*)(ws + 99757504);   // 65,536
    _Float16* Wt2       = (_Float16*)(ws + 99823040);   // 65,536

    const int TPB = 256;
    // CSR build (src-block-sorted rows, single-pass counting sort)
    k_part<<<P1_BLOCKS, P1_TPB, 0, stream>>>(src, dst, stage, pcnt);
    k_bucketsum<<<1, 256, 0, stream>>>(pcnt, bbase, row_start);
    k_build<<<NBUCK, P2_TPB, 0, stream>>>(stage, pcnt, bbase, row_start, esrc);

    // dtype prep
    k_cast<<<(N_NODES * F / 4 + TPB - 1) / TPB, TPB, 0, stream>>>(x, xh, N_NODES * F / 4);
    k_prepw<<<256, 256, 0, stream>>>(Ws1, Wn1, Ws2, Wn2, Wt1, Wt2);

    // layer 1
    k_agg<<<(N_NODES + 3) / 4, 256, 0, stream>>>((const f16x2*)xh, row_start, esrc,
                                                 (f16x2*)hneigh);
    k_gemm_mfma<false><<<(N_NODES + 127) / 128, 256, 0, stream>>>(
        xh, hneigh, Wt1, b1, h1, nullptr, nullptr, nullptr);
    // layer 2 + fused final projection
    k_agg<<<(N_NODES + 3) / 4, 256, 0, stream>>>((const f16x2*)h1, row_start, esrc,
                                                 (f16x2*)hneigh);
    k_gemm_mfma<true><<<(N_NODES + 127) / 128, 256, 0, stream>>>(
        h1, hneigh, Wt2, b2, nullptr, Wf, bf, out);
}